// Round 12
// baseline (156.594 us; speedup 1.0000x reference)
//
#include <hip/hip_runtime.h>

#define HDIM    256
#define HHALF   128
#define NTYPE   100
#define RPB     8      // crystals (rows) per block
#define S       260    // LDS h-row stride in floats
#define THREADS 512
#define PSTRIDE 33     // partials stride: (33*cg+o)%32 = (cg+o)%32 -> 2-way = free
#define REGION  2112   // 64 * 33 floats per K-group partial region
#define REP     8      // DIAGNOSTIC: layer-1 gemm repeated; dur = T + 7*t_layer1

typedef float f32x4_n __attribute__((ext_vector_type(4)));

__device__ __forceinline__ float silu_f(float x) {
    return x / (1.0f + __expf(-x));
}

#define LD4(p) (*(const float4*)(p))
#define FMA4(A, s, v) do { (A).x += (s)*(v).x; (A).y += (s)*(v).y; \
                           (A).z += (s)*(v).z; (A).w += (s)*(v).w; } while (0)

// 8 rows x 4 cols per thread over KT k-rows. Weights double-buffered in
// registers. Each W row is read by exactly ONE wave per block (no redundant
// L1 traffic). h reads are wave-uniform LDS broadcasts.
template<int KT>
__device__ __forceinline__ void gemm_8x4(
    const float* hbase,                 // &buf[kbase]; reads hbase + r*S + k
    const float* __restrict__ W,        // W + kbase*ldw + j0
    const int ldw, float4* acc)
{
    float4 wA0 = LD4(W);           float4 wA1 = LD4(W + ldw);
    float4 wA2 = LD4(W + 2 * ldw); float4 wA3 = LD4(W + 3 * ldw);
#pragma unroll 1
    for (int k4 = 0; k4 < KT - 4; k4 += 4) {
        const float* Wn = W + (size_t)(k4 + 4) * ldw;
        float4 wB0 = LD4(Wn);           float4 wB1 = LD4(Wn + ldw);
        float4 wB2 = LD4(Wn + 2 * ldw); float4 wB3 = LD4(Wn + 3 * ldw);
#pragma unroll
        for (int r = 0; r < 8; ++r) {
            float4 h4 = LD4(hbase + r * S + k4);
            FMA4(acc[r], h4.x, wA0); FMA4(acc[r], h4.y, wA1);
            FMA4(acc[r], h4.z, wA2); FMA4(acc[r], h4.w, wA3);
        }
        wA0 = wB0; wA1 = wB1; wA2 = wB2; wA3 = wB3;
    }
#pragma unroll
    for (int r = 0; r < 8; ++r) {
        float4 h4 = LD4(hbase + r * S + (KT - 4));
        FMA4(acc[r], h4.x, wA0); FMA4(acc[r], h4.y, wA1);
        FMA4(acc[r], h4.z, wA2); FMA4(acc[r], h4.w, wA3);
    }
}

__device__ __forceinline__ void part_wr(float* rp, const float4* acc) {
#pragma unroll
    for (int r = 0; r < 8; ++r) {
        rp[r*4+0] = acc[r].x; rp[r*4+1] = acc[r].y;
        rp[r*4+2] = acc[r].z; rp[r*4+3] = acc[r].w;
    }
}

__device__ __forceinline__ void part_add(const float* rbase, int nparts,
                                         int rstride, float4* acc) {
    for (int p = 0; p < nparts; ++p) {
        const float* rp = rbase + (size_t)p * rstride;
#pragma unroll
        for (int r = 0; r < 8; ++r) {
            acc[r].x += rp[r*4+0]; acc[r].y += rp[r*4+1];
            acc[r].z += rp[r*4+2]; acc[r].w += rp[r*4+3];
        }
    }
}

// One block = 8 crystals, 512 threads. DIAGNOSTIC build: layer-1 gemm x REP.
__global__ __launch_bounds__(THREADS, 4) void fused_kernel(
    const int* __restrict__ batch, int N,
    const float* __restrict__ t_emb,
    const float* __restrict__ w1a, const float* __restrict__ b1a,
    const float* __restrict__ w2a, const float* __restrict__ b2a,
    const float* __restrict__ wc1, const float* __restrict__ bc1,
    const float* __restrict__ wc2, const float* __restrict__ bc2,
    const float* __restrict__ wl1, const float* __restrict__ bl1,
    const float* __restrict__ wl2, const float* __restrict__ bl2,
    const float* __restrict__ wt,  const float* __restrict__ bt,
    float* __restrict__ out_coord,    // [N,3]
    float* __restrict__ cell_out,     // [B,6]
    f32x4_n* __restrict__ out_logits4)// [N,25] f4
{
    __shared__ float bufA[RPB * S];      // h0, then h
    __shared__ float bufB[RPB * S];      // h1, then gc(0..127)/gl(128..255)
    __shared__ float red[7 * REGION];    // 57.75 KB cross-K partials
    __shared__ float logits_s[RPB * 104];
    __shared__ float coord_s[RPB * 4];
    __shared__ int   lb_s[RPB + 1];
    __shared__ float cnt_s[RPB];

    const int tid = threadIdx.x;
    const int R0  = blockIdx.x * RPB;

    // atom ranges via binary search on sorted batch
    if (tid <= RPB) {
        int v = R0 + tid;
        int lo = 0, hi = N;
        while (lo < hi) { int mid = (lo + hi) >> 1; if (batch[mid] < v) lo = mid + 1; else hi = mid; }
        lb_s[tid] = lo;
    }

    // stage t_emb rows R0..R0+7 (one float4 per thread, coalesced)
    {
        const float4* src = (const float4*)(t_emb + (size_t)R0 * HDIM);
        int r = tid >> 6, kq = tid & 63;
        *(float4*)&bufA[r * S + kq * 4] = src[r * 64 + kq];
    }
    __syncthreads();
    if (tid < RPB) cnt_s[tid] = (float)(lb_s[tid + 1] - lb_s[tid]);

    const int cg  = tid & 63;    // col-group: j0..j0+3
    const int ksg = tid >> 6;    // K-group == wave id (0..7)
    const int j0  = cg * 4;

    float4 acc[8];

    // ---------------- layer 1 (xREP): h1 = silu(h0 @ w1a + b1a)  bufA -> bufB
    // DIAGNOSTIC: accumulate REP identical gemms then scale by 1/REP (exact
    // power of 2). Accumulation keeps every rep live -- no DCE.
    {
#pragma unroll
        for (int r = 0; r < 8; ++r) acc[r] = make_float4(0.f, 0.f, 0.f, 0.f);
#pragma unroll 1
        for (int rep = 0; rep < REP; ++rep) {
            gemm_8x4<32>(&bufA[ksg * 32], w1a + (size_t)(ksg * 32) * HDIM + j0, HDIM, acc);
        }
#pragma unroll
        for (int r = 0; r < 8; ++r) {
            acc[r].x *= (1.f / REP); acc[r].y *= (1.f / REP);
            acc[r].z *= (1.f / REP); acc[r].w *= (1.f / REP);
        }
        if (ksg) part_wr(&red[(ksg - 1) * REGION + cg * PSTRIDE], acc);
        __syncthreads();
        if (!ksg) {
            part_add(&red[cg * PSTRIDE], 7, REGION, acc);
            float4 b4 = LD4(b1a + j0);
#pragma unroll
            for (int r = 0; r < 8; ++r) {
                float4 v;
                v.x = silu_f(acc[r].x + b4.x); v.y = silu_f(acc[r].y + b4.y);
                v.z = silu_f(acc[r].z + b4.z); v.w = silu_f(acc[r].w + b4.w);
                *(float4*)&bufB[r * S + j0] = v;
            }
        }
        __syncthreads();
    }

    // ---------------- layer 2: h = h1 @ w2a + b2a          bufB -> bufA
    {
#pragma unroll
        for (int r = 0; r < 8; ++r) acc[r] = make_float4(0.f, 0.f, 0.f, 0.f);
        gemm_8x4<32>(&bufB[ksg * 32], w2a + (size_t)(ksg * 32) * HDIM + j0, HDIM, acc);
        if (ksg) part_wr(&red[(ksg - 1) * REGION + cg * PSTRIDE], acc);
        __syncthreads();
        if (!ksg) {
            part_add(&red[cg * PSTRIDE], 7, REGION, acc);
            float4 b4 = LD4(b2a + j0);
#pragma unroll
            for (int r = 0; r < 8; ++r) {
                float4 v;
                v.x = acc[r].x + b4.x; v.y = acc[r].y + b4.y;
                v.z = acc[r].z + b4.z; v.w = acc[r].w + b4.w;
                *(float4*)&bufA[r * S + j0] = v;
            }
        }
        __syncthreads();
    }

    // ---------------- logits: h @ wt + bt -> logits_s (LDS)
    {
        if (cg < 25) {
#pragma unroll
            for (int r = 0; r < 8; ++r) acc[r] = make_float4(0.f, 0.f, 0.f, 0.f);
            gemm_8x4<32>(&bufA[ksg * 32], wt + (size_t)(ksg * 32) * NTYPE + j0, NTYPE, acc);
            if (ksg) part_wr(&red[(ksg - 1) * REGION + cg * PSTRIDE], acc);
        }
        __syncthreads();
        if (!ksg && cg < 25) {
            part_add(&red[cg * PSTRIDE], 7, REGION, acc);
            float4 b4 = LD4(bt + j0);
#pragma unroll
            for (int r = 0; r < 8; ++r) {
                *(float4*)&logits_s[r * 104 + j0] =
                    make_float4(acc[r].x + b4.x, acc[r].y + b4.y,
                                acc[r].z + b4.z, acc[r].w + b4.w);
            }
        }
        __syncthreads();
    }

    // -------- OVERLAP: waves 0-1 head hidden GEMMs || waves 2-7 logits stream
    if (tid < 128) {
        const int  hcg = tid & 31;
        const int  hks = (tid >> 5) & 1;   // K-half: 128 rows each
        const bool ic  = (tid >= 64);
        const int  hj0 = hcg * 4;
        const float* W  = ic ? wl1 : wc1;
        const float* bb = ic ? bl1 : bc1;
        const int  rbase = ic ? 1056 : 0;  // 1056 = 32*33 floats per region

        float4 hacc[8];
#pragma unroll
        for (int r = 0; r < 8; ++r) hacc[r] = make_float4(0.f, 0.f, 0.f, 0.f);
        gemm_8x4<128>(&bufA[hks * 128], W + (size_t)(hks * 128) * HHALF + hj0,
                      HHALF, hacc);
        if (hks) part_wr(&red[rbase + hcg * PSTRIDE], hacc);
        __syncthreads();   // barrier A (store waves arrive after issuing stores)
        if (!hks) {
            part_add(&red[rbase + hcg * PSTRIDE], 1, 0, hacc);
            float4 b4 = LD4(bb + hj0);
            const int off = ic ? HHALF : 0;
#pragma unroll
            for (int r = 0; r < 8; ++r) {
                const float sc = ic ? cnt_s[r] : 1.f;
                float4 v;
                v.x = silu_f(hacc[r].x * sc + b4.x); v.y = silu_f(hacc[r].y * sc + b4.y);
                v.z = silu_f(hacc[r].z * sc + b4.z); v.w = silu_f(hacc[r].w * sc + b4.w);
                *(float4*)&bufB[r * S + off + hj0] = v;
            }
        }
    } else {
        // 384 threads stream per-atom logits (coalesced nontemporal f4 stores)
        const int st = tid - 128;
        const f32x4_n* ls4 = (const f32x4_n*)logits_s;   // row stride 26 f4
#pragma unroll 1
        for (int r = 0; r < RPB; ++r) {
            const int base = lb_s[r];
            const int tot  = (lb_s[r + 1] - base) * 25;
            const f32x4_n* lrow = ls4 + r * 26;
            for (int t = st; t < tot; t += 384) {
                unsigned a = (unsigned)t / 25u;
                unsigned q = (unsigned)t - a * 25u;
                f32x4_n v = lrow[q];
                __builtin_nontemporal_store(v, &out_logits4[(size_t)(base + a) * 25 + q]);
            }
        }
        __syncthreads();   // barrier A
    }
    __syncthreads();       // barrier B: bufB head outputs visible

    // ---------------- tiny heads: coord [8x3] -> coord_s, cell [8x6] -> global
    if (tid < 24) {
        int r = tid / 3, c = tid - 3 * r;
        float a = 0.f;
#pragma unroll 4
        for (int k = 0; k < HHALF; k += 4) {
            float4 hv = LD4(&bufB[r * S + k]);
            a += hv.x * wc2[(k + 0) * 3 + c] + hv.y * wc2[(k + 1) * 3 + c]
               + hv.z * wc2[(k + 2) * 3 + c] + hv.w * wc2[(k + 3) * 3 + c];
        }
        coord_s[r * 4 + c] = a + bc2[c];
    } else if (tid < 72) {
        int t2 = tid - 24;
        int r = t2 / 6, c = t2 - 6 * r;
        float a = 0.f;
#pragma unroll 4
        for (int k = 0; k < HHALF; k += 4) {
            float4 hv = LD4(&bufB[r * S + HHALF + k]);
            a += hv.x * wl2[(k + 0) * 6 + c] + hv.y * wl2[(k + 1) * 6 + c]
               + hv.z * wl2[(k + 2) * 6 + c] + hv.w * wl2[(k + 3) * 6 + c];
        }
        cell_out[(size_t)(R0 + r) * 6 + c] = a + bl2[c];
    }
    __syncthreads();

    // ---------------- per-atom coord stream (6 MB, coalesced)
#pragma unroll 1
    for (int r = 0; r < RPB; ++r) {
        const int base = lb_s[r];
        const int tot3 = (lb_s[r + 1] - base) * 3;
        const float c0 = coord_s[r * 4 + 0];
        const float c1 = coord_s[r * 4 + 1];
        const float c2 = coord_s[r * 4 + 2];
        float* oc = out_coord + (size_t)base * 3;
        for (int t = tid; t < tot3; t += THREADS) {
            unsigned a = (unsigned)t / 3u;
            unsigned c = (unsigned)t - a * 3u;
            float v = (c == 0) ? c0 : (c == 1) ? c1 : c2;
            __builtin_nontemporal_store(v, &oc[t]);
        }
    }
}

extern "C" void kernel_launch(void* const* d_in, const int* in_sizes, int n_in,
                              void* d_out, int out_size, void* d_ws, size_t ws_size,
                              hipStream_t stream)
{
    const int*   batch = (const int*)d_in[1];
    const float* t_emb = (const float*)d_in[3];
    const float* w1a = (const float*)d_in[4];
    const float* b1a = (const float*)d_in[5];
    const float* w2a = (const float*)d_in[6];
    const float* b2a = (const float*)d_in[7];
    const float* wc1 = (const float*)d_in[8];
    const float* bc1 = (const float*)d_in[9];
    const float* wc2 = (const float*)d_in[10];
    const float* bc2 = (const float*)d_in[11];
    const float* wl1 = (const float*)d_in[12];
    const float* bl1 = (const float*)d_in[13];
    const float* wl2 = (const float*)d_in[14];
    const float* bl2 = (const float*)d_in[15];
    const float* wt  = (const float*)d_in[16];
    const float* bt  = (const float*)d_in[17];

    const int N = in_sizes[1];        // 500000
    const int B = in_sizes[2] / 9;    // 4096

    float* out        = (float*)d_out;
    float* out_coord  = out;                                   // [N,3]
    float* cell_out   = out + (size_t)N * 3;                   // [B,6]
    float* out_logits = out + (size_t)N * 3 + (size_t)B * 6;   // [N,100]

    fused_kernel<<<B / RPB, THREADS, 0, stream>>>(
        batch, N, t_emb,
        w1a, b1a, w2a, b2a,
        wc1, bc1, wc2, bc2,
        wl1, bl1, wl2, bl2,
        wt, bt,
        out_coord, cell_out, (f32x4_n*)out_logits);
}

// Round 13
// 85.582 us; speedup vs baseline: 1.8298x; 1.8298x over previous
//
#include <hip/hip_runtime.h>

#define HDIM    256
#define HHALF   128
#define NTYPE   100
#define RPB     4      // crystals per block
#define S       260    // LDS h-row stride in floats
#define THREADS 256
#define REGION8 1056   // 32 slots * 33 (32-float partials, main gemms)
#define REGION4 544    // 32 slots * 17 (16-float partials, logits)

typedef float f32x4_n __attribute__((ext_vector_type(4)));

__device__ __forceinline__ float silu_f(float x) {
    return x / (1.0f + __expf(-x));
}

#define LD4(p) (*(const float4*)(p))
#define FMA4(A, s, v) do { (A).x += (s)*(v).x; (A).y += (s)*(v).y; \
                           (A).z += (s)*(v).z; (A).w += (s)*(v).w; } while (0)

// ---- main gemm: 4 rows x 8 cols (cols j0..j0+3 and j0+128..j0+131), KT=32.
// h (LDS) prefetched one k4-step ahead into registers; weights read once per
// block (dedup preserved). FMA:LDS-read = 32:1 (was 16:1).
#define FMABLK8(H0,H1,H2,H3) do { \
    FMA4(acc[0],H0.x,w0l); FMA4(acc[1],H0.x,w0h); \
    FMA4(acc[0],H0.y,w1l); FMA4(acc[1],H0.y,w1h); \
    FMA4(acc[0],H0.z,w2l); FMA4(acc[1],H0.z,w2h); \
    FMA4(acc[0],H0.w,w3l); FMA4(acc[1],H0.w,w3h); \
    FMA4(acc[2],H1.x,w0l); FMA4(acc[3],H1.x,w0h); \
    FMA4(acc[2],H1.y,w1l); FMA4(acc[3],H1.y,w1h); \
    FMA4(acc[2],H1.z,w2l); FMA4(acc[3],H1.z,w2h); \
    FMA4(acc[2],H1.w,w3l); FMA4(acc[3],H1.w,w3h); \
    FMA4(acc[4],H2.x,w0l); FMA4(acc[5],H2.x,w0h); \
    FMA4(acc[4],H2.y,w1l); FMA4(acc[5],H2.y,w1h); \
    FMA4(acc[4],H2.z,w2l); FMA4(acc[5],H2.z,w2h); \
    FMA4(acc[4],H2.w,w3l); FMA4(acc[5],H2.w,w3h); \
    FMA4(acc[6],H3.x,w0l); FMA4(acc[7],H3.x,w0h); \
    FMA4(acc[6],H3.y,w1l); FMA4(acc[7],H3.y,w1h); \
    FMA4(acc[6],H3.z,w2l); FMA4(acc[7],H3.z,w2h); \
    FMA4(acc[6],H3.w,w3l); FMA4(acc[7],H3.w,w3h); } while (0)

__device__ __forceinline__ void gemm_main(
    const float* hb, const float* __restrict__ W, float4* acc)
{
    float4 ha0=LD4(hb), ha1=LD4(hb+S), ha2=LD4(hb+2*S), ha3=LD4(hb+3*S);
#pragma unroll 1
    for (int k4 = 0; k4 < 28; k4 += 4) {
        float4 hn0=LD4(hb+k4+4),     hn1=LD4(hb+S+k4+4),
               hn2=LD4(hb+2*S+k4+4), hn3=LD4(hb+3*S+k4+4);
        const float* w = W + (size_t)k4 * HDIM;
        float4 w0l=LD4(w),        w0h=LD4(w+128);
        float4 w1l=LD4(w+HDIM),   w1h=LD4(w+HDIM+128);
        float4 w2l=LD4(w+2*HDIM), w2h=LD4(w+2*HDIM+128);
        float4 w3l=LD4(w+3*HDIM), w3h=LD4(w+3*HDIM+128);
        FMABLK8(ha0, ha1, ha2, ha3);
        ha0=hn0; ha1=hn1; ha2=hn2; ha3=hn3;
    }
    {
        const float* w = W + (size_t)28 * HDIM;
        float4 w0l=LD4(w),        w0h=LD4(w+128);
        float4 w1l=LD4(w+HDIM),   w1h=LD4(w+HDIM+128);
        float4 w2l=LD4(w+2*HDIM), w2h=LD4(w+2*HDIM+128);
        float4 w3l=LD4(w+3*HDIM), w3h=LD4(w+3*HDIM+128);
        FMABLK8(ha0, ha1, ha2, ha3);
    }
}

// ---- small gemm: 4 rows x 4 cols, runtime ldw, KT k-rows
#define FMABLK4(H0,H1,H2,H3) do { \
    FMA4(a[0],H0.x,w0); FMA4(a[0],H0.y,w1); FMA4(a[0],H0.z,w2); FMA4(a[0],H0.w,w3); \
    FMA4(a[1],H1.x,w0); FMA4(a[1],H1.y,w1); FMA4(a[1],H1.z,w2); FMA4(a[1],H1.w,w3); \
    FMA4(a[2],H2.x,w0); FMA4(a[2],H2.y,w1); FMA4(a[2],H2.z,w2); FMA4(a[2],H2.w,w3); \
    FMA4(a[3],H3.x,w0); FMA4(a[3],H3.y,w1); FMA4(a[3],H3.z,w2); FMA4(a[3],H3.w,w3); } while (0)

template<int KT>
__device__ __forceinline__ void gemm_4x4(
    const float* hb, const float* __restrict__ W, const int ldw, float4* a)
{
    float4 ha0=LD4(hb), ha1=LD4(hb+S), ha2=LD4(hb+2*S), ha3=LD4(hb+3*S);
#pragma unroll 1
    for (int k4 = 0; k4 < KT - 4; k4 += 4) {
        float4 hn0=LD4(hb+k4+4),     hn1=LD4(hb+S+k4+4),
               hn2=LD4(hb+2*S+k4+4), hn3=LD4(hb+3*S+k4+4);
        const float* w = W + (size_t)k4 * ldw;
        float4 w0=LD4(w), w1=LD4(w+ldw), w2=LD4(w+2*ldw), w3=LD4(w+3*ldw);
        FMABLK4(ha0, ha1, ha2, ha3);
        ha0=hn0; ha1=hn1; ha2=hn2; ha3=hn3;
    }
    {
        const float* w = W + (size_t)(KT-4) * ldw;
        float4 w0=LD4(w), w1=LD4(w+ldw), w2=LD4(w+2*ldw), w3=LD4(w+3*ldw);
        FMABLK4(ha0, ha1, ha2, ha3);
    }
}

// intra-wave pair reduce over ksg (lanes 0-31 <-> 32-63)
__device__ __forceinline__ void shfl_reduce(float4* a, int n) {
#pragma unroll
    for (int i = 0; i < n; ++i) {
        a[i].x += __shfl_xor(a[i].x, 32);
        a[i].y += __shfl_xor(a[i].y, 32);
        a[i].z += __shfl_xor(a[i].z, 32);
        a[i].w += __shfl_xor(a[i].w, 32);
    }
}

__global__ __launch_bounds__(THREADS, 4) void fused_kernel(
    const int* __restrict__ batch, int N,
    const float* __restrict__ t_emb,
    const float* __restrict__ w1a, const float* __restrict__ b1a,
    const float* __restrict__ w2a, const float* __restrict__ b2a,
    const float* __restrict__ wc1, const float* __restrict__ bc1,
    const float* __restrict__ wc2, const float* __restrict__ bc2,
    const float* __restrict__ wl1, const float* __restrict__ bl1,
    const float* __restrict__ wl2, const float* __restrict__ bl2,
    const float* __restrict__ wt,  const float* __restrict__ bt,
    float* __restrict__ out_coord,    // [N,3]
    float* __restrict__ cell_out,     // [B,6]
    f32x4_n* __restrict__ out_logits4)// [N,25] f4
{
    __shared__ float bufA[RPB * S];        // h0, then h
    __shared__ float bufB[RPB * S];        // h1, then gc(0..127)/gl(128..255)
    __shared__ float red[3 * REGION8];     // 12.4 KB pair-sum partials
    __shared__ float logits_s[RPB * 104];
    __shared__ float coord_s[RPB * 4];
    __shared__ int   lb_s[RPB + 1];
    __shared__ float cnt_s[RPB];

    const int tid = threadIdx.x;
    const int R0  = blockIdx.x * RPB;

    if (tid <= RPB) {
        int v = R0 + tid;
        int lo = 0, hi = N;
        while (lo < hi) { int mid = (lo + hi) >> 1; if (batch[mid] < v) lo = mid + 1; else hi = mid; }
        lb_s[tid] = lo;
    }
    {   // stage t_emb rows R0..R0+3 (one f4/thread, coalesced)
        const float4* src = (const float4*)(t_emb + (size_t)R0 * HDIM);
        int r = tid >> 6, kq = tid & 63;
        *(float4*)&bufA[r * S + kq * 4] = src[r * 64 + kq];
    }
    __syncthreads();
    if (tid < RPB) cnt_s[tid] = (float)(lb_s[tid + 1] - lb_s[tid]);

    const int cg  = tid & 31;    // 32 col-groups
    const int ksg = tid >> 5;    // 8 K-groups (pairs share a wave)
    const int wv  = tid >> 6;    // wave id 0..3
    const int j0  = cg * 4;      // low col; high col = j0+128
    const bool lo_half = !(tid & 32);

    float4 acc[8];

#define MAIN_REDUCE_STORE(BIAS, DST, ACT) do { \
    shfl_reduce(acc, 8); \
    if (wv && lo_half) { float* rp = &red[(wv - 1) * REGION8 + cg * 33]; \
        _Pragma("unroll") for (int r = 0; r < 4; ++r) { \
            rp[r*8+0]=acc[2*r].x; rp[r*8+1]=acc[2*r].y; rp[r*8+2]=acc[2*r].z; rp[r*8+3]=acc[2*r].w; \
            rp[r*8+4]=acc[2*r+1].x; rp[r*8+5]=acc[2*r+1].y; rp[r*8+6]=acc[2*r+1].z; rp[r*8+7]=acc[2*r+1].w; } } \
    __syncthreads(); \
    if (tid < 32) { \
        _Pragma("unroll") for (int p = 0; p < 3; ++p) { const float* rp = &red[p * REGION8 + cg * 33]; \
            _Pragma("unroll") for (int r = 0; r < 4; ++r) { \
                acc[2*r].x+=rp[r*8+0]; acc[2*r].y+=rp[r*8+1]; acc[2*r].z+=rp[r*8+2]; acc[2*r].w+=rp[r*8+3]; \
                acc[2*r+1].x+=rp[r*8+4]; acc[2*r+1].y+=rp[r*8+5]; acc[2*r+1].z+=rp[r*8+6]; acc[2*r+1].w+=rp[r*8+7]; } } \
        float4 bl = LD4((BIAS) + j0), bh = LD4((BIAS) + j0 + 128); \
        _Pragma("unroll") for (int r = 0; r < 4; ++r) { \
            float4 vl, vh; \
            vl.x=acc[2*r].x+bl.x; vl.y=acc[2*r].y+bl.y; vl.z=acc[2*r].z+bl.z; vl.w=acc[2*r].w+bl.w; \
            vh.x=acc[2*r+1].x+bh.x; vh.y=acc[2*r+1].y+bh.y; vh.z=acc[2*r+1].z+bh.z; vh.w=acc[2*r+1].w+bh.w; \
            if (ACT) { vl.x=silu_f(vl.x); vl.y=silu_f(vl.y); vl.z=silu_f(vl.z); vl.w=silu_f(vl.w); \
                       vh.x=silu_f(vh.x); vh.y=silu_f(vh.y); vh.z=silu_f(vh.z); vh.w=silu_f(vh.w); } \
            *(float4*)&(DST)[r * S + j0] = vl; \
            *(float4*)&(DST)[r * S + j0 + 128] = vh; } } \
    __syncthreads(); } while (0)

    // ---------------- layer 1: h1 = silu(h0 @ w1a + b1a)   bufA -> bufB
#pragma unroll
    for (int i = 0; i < 8; ++i) acc[i] = make_float4(0.f, 0.f, 0.f, 0.f);
    gemm_main(&bufA[ksg * 32], w1a + (size_t)(ksg * 32) * HDIM + j0, acc);
    MAIN_REDUCE_STORE(b1a, bufB, true);

    // ---------------- layer 2: h = h1 @ w2a + b2a          bufB -> bufA
#pragma unroll
    for (int i = 0; i < 8; ++i) acc[i] = make_float4(0.f, 0.f, 0.f, 0.f);
    gemm_main(&bufB[ksg * 32], w2a + (size_t)(ksg * 32) * HDIM + j0, acc);
    MAIN_REDUCE_STORE(b2a, bufA, false);

    // ---------------- logits: h @ wt + bt -> logits_s
    {
        float4 a[4];
#pragma unroll
        for (int i = 0; i < 4; ++i) a[i] = make_float4(0.f, 0.f, 0.f, 0.f);
        if (cg < 25)
            gemm_4x4<32>(&bufA[ksg * 32], wt + (size_t)(ksg * 32) * NTYPE + j0, NTYPE, a);
        shfl_reduce(a, 4);
        if (wv && lo_half && cg < 25) {
            float* rp = &red[(wv - 1) * REGION4 + cg * 17];
#pragma unroll
            for (int r = 0; r < 4; ++r) {
                rp[r*4+0]=a[r].x; rp[r*4+1]=a[r].y; rp[r*4+2]=a[r].z; rp[r*4+3]=a[r].w;
            }
        }
        __syncthreads();
        if (tid < 25) {
#pragma unroll
            for (int p = 0; p < 3; ++p) {
                const float* rp = &red[p * REGION4 + cg * 17];
#pragma unroll
                for (int r = 0; r < 4; ++r) {
                    a[r].x+=rp[r*4+0]; a[r].y+=rp[r*4+1]; a[r].z+=rp[r*4+2]; a[r].w+=rp[r*4+3];
                }
            }
            float4 b4 = LD4(bt + j0);
#pragma unroll
            for (int r = 0; r < 4; ++r)
                *(float4*)&logits_s[r * 104 + j0] =
                    make_float4(a[r].x + b4.x, a[r].y + b4.y, a[r].z + b4.z, a[r].w + b4.w);
        }
        __syncthreads();
    }

    // -------- OVERLAP: waves 0-1 head hidden GEMMs (shfl reduce, no barrier)
    // -------- || waves 2-3 stream per-atom logits (nontemporal)
    if (tid < 128) {
        const bool ic  = (tid >= 64);          // wave0 coord, wave1 cell
        const int  hcg = tid & 31;
        const int  hks = (tid >> 5) & 1;       // K-half (128 rows)
        const int  hj0 = hcg * 4;
        const float* W  = ic ? wl1 : wc1;
        const float* bb = ic ? bl1 : bc1;

        float4 a[4];
#pragma unroll
        for (int i = 0; i < 4; ++i) a[i] = make_float4(0.f, 0.f, 0.f, 0.f);
        gemm_4x4<128>(&bufA[hks * 128], W + (size_t)(hks * 128) * HHALF + hj0, HHALF, a);
        shfl_reduce(a, 4);                     // hks pair within the wave
        if (!hks) {
            float4 b4 = LD4(bb + hj0);
            const int off = ic ? HHALF : 0;
#pragma unroll
            for (int r = 0; r < 4; ++r) {
                // segment_sum == count*h; scale commutes through the dot
                const float sc = ic ? cnt_s[r] : 1.f;
                float4 v;
                v.x = silu_f(a[r].x * sc + b4.x); v.y = silu_f(a[r].y * sc + b4.y);
                v.z = silu_f(a[r].z * sc + b4.z); v.w = silu_f(a[r].w * sc + b4.w);
                *(float4*)&bufB[r * S + off + hj0] = v;
            }
        }
    } else {
        const int st = tid - 128;              // 128 streaming threads
        const f32x4_n* ls4 = (const f32x4_n*)logits_s;   // row stride 26 f4
#pragma unroll 1
        for (int r = 0; r < RPB; ++r) {
            const int base = lb_s[r];
            const int tot  = (lb_s[r + 1] - base) * 25;
            const f32x4_n* lrow = ls4 + r * 26;
            for (int t = st; t < tot; t += 128) {
                unsigned a = (unsigned)t / 25u;
                unsigned q = (unsigned)t - a * 25u;
                f32x4_n v = lrow[q];
                __builtin_nontemporal_store(v, &out_logits4[(size_t)(base + a) * 25 + q]);
            }
        }
    }
    __syncthreads();

    // ---------------- tiny heads
    if (tid < 12) {
        int r = tid / 3, c = tid - 3 * r;
        float a = 0.f;
#pragma unroll 4
        for (int k = 0; k < HHALF; k += 4) {
            float4 hv = LD4(&bufB[r * S + k]);
            a += hv.x * wc2[(k + 0) * 3 + c] + hv.y * wc2[(k + 1) * 3 + c]
               + hv.z * wc2[(k + 2) * 3 + c] + hv.w * wc2[(k + 3) * 3 + c];
        }
        coord_s[r * 4 + c] = a + bc2[c];
    } else if (tid < 36) {
        int t2 = tid - 12;
        int r = t2 / 6, c = t2 - 6 * r;
        float a = 0.f;
#pragma unroll 4
        for (int k = 0; k < HHALF; k += 4) {
            float4 hv = LD4(&bufB[r * S + HHALF + k]);
            a += hv.x * wl2[(k + 0) * 6 + c] + hv.y * wl2[(k + 1) * 6 + c]
               + hv.z * wl2[(k + 2) * 6 + c] + hv.w * wl2[(k + 3) * 6 + c];
        }
        cell_out[(size_t)(R0 + r) * 6 + c] = a + bl2[c];
    }
    __syncthreads();

    // ---------------- per-atom coord stream (6 MB, coalesced)
#pragma unroll 1
    for (int r = 0; r < RPB; ++r) {
        const int base = lb_s[r];
        const int tot3 = (lb_s[r + 1] - base) * 3;
        const float c0 = coord_s[r * 4 + 0];
        const float c1 = coord_s[r * 4 + 1];
        const float c2 = coord_s[r * 4 + 2];
        float* oc = out_coord + (size_t)base * 3;
        for (int t = tid; t < tot3; t += THREADS) {
            unsigned a = (unsigned)t / 3u;
            unsigned c = (unsigned)t - a * 3u;
            float v = (c == 0) ? c0 : (c == 1) ? c1 : c2;
            __builtin_nontemporal_store(v, &oc[t]);
        }
    }
}

extern "C" void kernel_launch(void* const* d_in, const int* in_sizes, int n_in,
                              void* d_out, int out_size, void* d_ws, size_t ws_size,
                              hipStream_t stream)
{
    const int*   batch = (const int*)d_in[1];
    const float* t_emb = (const float*)d_in[3];
    const float* w1a = (const float*)d_in[4];
    const float* b1a = (const float*)d_in[5];
    const float* w2a = (const float*)d_in[6];
    const float* b2a = (const float*)d_in[7];
    const float* wc1 = (const float*)d_in[8];
    const float* bc1 = (const float*)d_in[9];
    const float* wc2 = (const float*)d_in[10];
    const float* bc2 = (const float*)d_in[11];
    const float* wl1 = (const float*)d_in[12];
    const float* bl1 = (const float*)d_in[13];
    const float* wl2 = (const float*)d_in[14];
    const float* bl2 = (const float*)d_in[15];
    const float* wt  = (const float*)d_in[16];
    const float* bt  = (const float*)d_in[17];

    const int N = in_sizes[1];        // 500000
    const int B = in_sizes[2] / 9;    // 4096

    float* out        = (float*)d_out;
    float* out_coord  = out;                                   // [N,3]
    float* cell_out   = out + (size_t)N * 3;                   // [B,6]
    float* out_logits = out + (size_t)N * 3 + (size_t)B * 6;   // [N,100]

    fused_kernel<<<B / RPB, THREADS, 0, stream>>>(
        batch, N, t_emb,
        w1a, b1a, w2a, b2a,
        wc1, bc1, wc2, bc2,
        wl1, bl1, wl2, bl2,
        wt, bt,
        out_coord, cell_out, (f32x4_n*)out_logits);
}